// Round 1
// baseline (255.313 us; speedup 1.0000x reference)
//
#include <hip/hip_runtime.h>
#include <hip/hip_bf16.h>
#include <math.h>

#define ALPHA 0.2f
#define LOG2E 1.4426950408889634f

constexpr int B_ = 4, N_ = 2048, F_ = 256, T_ = 8, H_ = 4, D_ = 64;
constexpr int FT = F_ + T_; // 264

using short8  = __attribute__((ext_vector_type(8))) short;
using float4v = __attribute__((ext_vector_type(4))) float;
using int4v   = __attribute__((ext_vector_type(4))) int;
using uint4v  = __attribute__((ext_vector_type(4))) unsigned;

#if __has_builtin(__builtin_amdgcn_exp2f)
#define EXP2F(x) __builtin_amdgcn_exp2f(x)
#else
#define EXP2F(x) exp2f(x)
#endif

// ---- workspace byte offsets (all 16B aligned) ----
#define V1_OFF   0u            // 4*264 f32
#define V2_OFF   4224u         // 4*264 f32
#define E1_OFF   8448u         // 4*4*2048 f32 (pre-scaled by log2e)
#define E2_OFF   139520u       // 4*4*2048 f32
#define C_OFF    270592u       // 4*4*2048 f32 : 1/s per column
#define PART_OFF 401664u       // 16*4*4*2048 f32 partial column sums
#define WT_OFF   2498816u      // 256*256 bf16 : W transposed [hd][f]
#define WHT_OFF  2629888u      // 4*256*2048 bf16 : Wh transposed [b][hd][j]

__device__ inline unsigned short f2bf_rne(float f) {
    unsigned u = __builtin_bit_cast(unsigned, f);
    u += 0x7FFFu + ((u >> 16) & 1u);
    return (unsigned short)(u >> 16);
}
__device__ inline unsigned pack_bf_rne(float f0, float f1) {
    return (unsigned)f2bf_rne(f0) | ((unsigned)f2bf_rne(f1) << 16);
}
__device__ inline unsigned pack_bf_trunc(float f0, float f1) {
    unsigned u0 = __builtin_bit_cast(unsigned, f0);
    unsigned u1 = __builtin_bit_cast(unsigned, f1);
    return (u0 >> 16) | (u1 & 0xFFFF0000u);
}

// K1: v1[h,f] = log2e * sum_d Wq[h,f,d]*a[h,d] ; v2 from Wk with a[h,64+d]
__global__ __launch_bounds__(256) void k_prep_v(const float* __restrict__ Wq,
                                                const float* __restrict__ Wk,
                                                const float* __restrict__ a,
                                                float* __restrict__ v1,
                                                float* __restrict__ v2) {
    int tid = blockIdx.x * 256 + threadIdx.x;
    if (tid >= 2 * H_ * FT) return;
    int sel = tid / (H_ * FT);
    int r = tid - sel * (H_ * FT);
    int h = r / FT, f = r - h * FT;
    const float* W = sel ? Wk : Wq;
    const float* av = a + h * 2 * D_ + sel * D_;
    const float* wrow = W + (size_t)(h * FT + f) * D_;
    float acc = 0.f;
    for (int d = 0; d < D_; ++d) acc += wrow[d] * av[d];
    (sel ? v2 : v1)[h * FT + f] = acc * LOG2E;
}

// K1b: WT[hd][f] = bf16(W[h][f][d])
__global__ __launch_bounds__(256) void k_prep_wt(const float* __restrict__ W,
                                                 unsigned short* __restrict__ WT) {
    int tid = blockIdx.x * 256 + threadIdx.x;  // 65536 total
    int hd = tid >> 8, f = tid & 255;
    int h = hd >> 6, d = hd & 63;
    WT[(size_t)hd * F_ + f] = f2bf_rne(W[((size_t)h * F_ + f) * D_ + d]);
}

// K2: e1'[b,h,n], e2'[b,h,n] — one wave per (b,n)
__global__ __launch_bounds__(256) void k_e12(const float* __restrict__ x,
                                             const float* __restrict__ oh,
                                             const float* __restrict__ v1,
                                             const float* __restrict__ v2,
                                             float* __restrict__ e1,
                                             float* __restrict__ e2) {
    int lane = threadIdx.x & 63;
    int w = threadIdx.x >> 6;
    int bn = blockIdx.x * 4 + w;
    int b = bn >> 11, n = bn & (N_ - 1);
    float a1h[H_] = {0.f, 0.f, 0.f, 0.f};
    float a2h[H_] = {0.f, 0.f, 0.f, 0.f};
    const float* xrow = x + (size_t)(b * N_ + n) * F_;
    for (int c = 0; c < 4; ++c) {
        int f = c * 64 + lane;
        float xv = xrow[f];
        #pragma unroll
        for (int h = 0; h < H_; ++h) {
            a1h[h] += xv * v1[h * FT + f];
            a2h[h] += xv * v2[h * FT + f];
        }
    }
    if (lane < T_) {
        float ov = oh[(size_t)(b * N_ + n) * T_ + lane];
        #pragma unroll
        for (int h = 0; h < H_; ++h) {
            a1h[h] += ov * v1[h * FT + F_ + lane];
            a2h[h] += ov * v2[h * FT + F_ + lane];
        }
    }
    #pragma unroll
    for (int off = 32; off; off >>= 1) {
        #pragma unroll
        for (int h = 0; h < H_; ++h) {
            a1h[h] += __shfl_xor(a1h[h], off, 64);
            a2h[h] += __shfl_xor(a2h[h], off, 64);
        }
    }
    if (lane == 0) {
        #pragma unroll
        for (int h = 0; h < H_; ++h) {
            e1[(size_t)(b * H_ + h) * N_ + n] = a1h[h];
            e2[(size_t)(b * H_ + h) * N_ + n] = a2h[h];
        }
    }
}

// K3: WhT[b][hd][j] = bf16( sum_f x[b,j,f] * W[h,f,d] )  via MFMA, A=WT rows, B=x rows
__global__ __launch_bounds__(256) void k_wht(const float* __restrict__ x,
                                             const unsigned short* __restrict__ WT,
                                             unsigned short* __restrict__ WhT) {
    int lane = threadIdx.x;       // 64
    int h = threadIdx.y;          // 4
    int jt = blockIdx.x;          // 128
    int b  = blockIdx.y;          // 4
    int j0 = jt * 16;
    int m = lane & 15, quad = lane >> 4;
    float4v zero = {0.f, 0.f, 0.f, 0.f};
    float4v acc[4] = {zero, zero, zero, zero};
    for (int f0 = 0; f0 < F_; f0 += 32) {
        // B fragment: B[k=f][n=j] = x[b][j0+(lane&15)][f0+quad*8 + 0..7]
        const float* xp = x + (size_t)(b * N_ + j0 + m) * F_ + f0 + quad * 8;
        float4v xlo = *(const float4v*)xp;
        float4v xhi = *(const float4v*)(xp + 4);
        uint4v bp = {pack_bf_rne(xlo[0], xlo[1]), pack_bf_rne(xlo[2], xlo[3]),
                     pack_bf_rne(xhi[0], xhi[1]), pack_bf_rne(xhi[2], xhi[3])};
        short8 bfrag = __builtin_bit_cast(short8, bp);
        #pragma unroll
        for (int mt = 0; mt < 4; ++mt) {
            // A fragment: A[m=hd][k=f], rows of WT (contiguous 16B)
            const unsigned short* ap =
                WT + (size_t)(h * 64 + mt * 16 + m) * F_ + f0 + quad * 8;
            short8 afrag = *(const short8*)ap;
            acc[mt] = __builtin_amdgcn_mfma_f32_16x16x32_bf16(afrag, bfrag, acc[mt], 0, 0, 0);
        }
    }
    #pragma unroll
    for (int mt = 0; mt < 4; ++mt) {
        #pragma unroll
        for (int reg = 0; reg < 4; ++reg) {
            int hd = h * 64 + mt * 16 + quad * 4 + reg;  // D row
            WhT[((size_t)b * 256 + hd) * N_ + j0 + m] = f2bf_rne(acc[mt][reg]);
        }
    }
}

// K4: partial column sums s[b,h,j] over an i-chunk
__global__ __launch_bounds__(256) void k_colsum(const int* __restrict__ adj,
                                                const float* __restrict__ e1,
                                                const float* __restrict__ e2,
                                                float* __restrict__ part) {
    int tid = threadIdx.x;   // 256
    int jt = blockIdx.x;     // 8
    int b  = blockIdx.y;     // 4
    int ic = blockIdx.z;     // 16
    int j = jt * 256 + tid;
    const float* e1b = e1 + (size_t)(b * H_) * N_;
    float e2h[H_], s[H_] = {0.f, 0.f, 0.f, 0.f};
    #pragma unroll
    for (int h = 0; h < H_; ++h) e2h[h] = e2[(size_t)(b * H_ + h) * N_ + j];
    int i0 = ic * 128;
    const int* ap = adj + ((size_t)b * N_ + i0) * N_ + j;
    #pragma unroll 4
    for (int i = i0; i < i0 + 128; ++i) {
        int av = *ap;
        ap += N_;
        #pragma unroll
        for (int h = 0; h < H_; ++h) {
            float z = e1b[h * N_ + i] + e2h[h];
            float t = EXP2F(fmaxf(z, ALPHA * z));
            s[h] += (av != 0) ? t : 0.f;
        }
    }
    #pragma unroll
    for (int h = 0; h < H_; ++h)
        part[((size_t)(ic * B_ + b) * H_ + h) * N_ + j] = s[h];
}

// K4b: c = s>0 ? 1/s : 0
__global__ __launch_bounds__(256) void k_recip(const float* __restrict__ part,
                                               float* __restrict__ c) {
    int tid = blockIdx.x * 256 + threadIdx.x;  // 32768
    float s = 0.f;
    #pragma unroll
    for (int ic = 0; ic < 16; ++ic) s += part[(size_t)ic * (B_ * H_ * N_) + tid];
    c[tid] = (s > 0.f) ? 1.f / s : 0.f;
}

// K6: h_prime[b,h,i,d] = sum_j att * Wh ; att rebuilt in-register as bf16 A-frags.
// block = (64,4): wave <-> h (adj tile shared via L1). 16 i-rows per block.
__global__ __launch_bounds__(256) void k_main(const int* __restrict__ adj,
                                              const float* __restrict__ e1,
                                              const float* __restrict__ e2,
                                              const float* __restrict__ cinv,
                                              const unsigned short* __restrict__ WhT,
                                              float* __restrict__ out) {
    int lane = threadIdx.x;   // 64
    int h = threadIdx.y;      // 4
    int it = blockIdx.x;      // 128
    int b  = blockIdx.y;      // 4
    int I0 = it * 16;
    int m = lane & 15, quad = lane >> 4;

    float e1v = e1[(size_t)(b * H_ + h) * N_ + I0 + m];
    const float* e2p = e2 + (size_t)(b * H_ + h) * N_;
    const float* cp  = cinv + (size_t)(b * H_ + h) * N_;
    const int* arow = adj + ((size_t)b * N_ + I0 + m) * N_;
    const unsigned short* bbase = WhT + (size_t)(b * H_ + h) * 64 * N_;

    float4v zero = {0.f, 0.f, 0.f, 0.f};
    float4v acc[4] = {zero, zero, zero, zero};

    for (int jb = 0; jb < N_; jb += 32) {
        int jq = jb + quad * 8;
        int4v a0 = *(const int4v*)(arow + jq);
        int4v a1 = *(const int4v*)(arow + jq + 4);
        float4v ez0 = *(const float4v*)(e2p + jq);
        float4v ez1 = *(const float4v*)(e2p + jq + 4);
        float4v c0 = *(const float4v*)(cp + jq);
        float4v c1 = *(const float4v*)(cp + jq + 4);

        float w[8];
        #pragma unroll
        for (int t = 0; t < 4; ++t) {
            float z = e1v + ez0[t];
            float p = EXP2F(fmaxf(z, ALPHA * z));
            w[t] = (a0[t] != 0) ? p * c0[t] : 0.f;
        }
        #pragma unroll
        for (int t = 0; t < 4; ++t) {
            float z = e1v + ez1[t];
            float p = EXP2F(fmaxf(z, ALPHA * z));
            w[4 + t] = (a1[t] != 0) ? p * c1[t] : 0.f;
        }
        uint4v apk = {pack_bf_trunc(w[0], w[1]), pack_bf_trunc(w[2], w[3]),
                      pack_bf_trunc(w[4], w[5]), pack_bf_trunc(w[6], w[7])};
        short8 afrag = __builtin_bit_cast(short8, apk);

        #pragma unroll
        for (int dt = 0; dt < 4; ++dt) {
            // B[k=j][n=d] from WhT row d = dt*16 + (lane&15), cols jq..jq+7 (16B)
            const unsigned short* bp = bbase + (size_t)(dt * 16 + m) * N_ + jq;
            short8 bfrag = *(const short8*)bp;
            acc[dt] = __builtin_amdgcn_mfma_f32_16x16x32_bf16(afrag, bfrag, acc[dt], 0, 0, 0);
        }
    }

    #pragma unroll
    for (int dt = 0; dt < 4; ++dt) {
        #pragma unroll
        for (int reg = 0; reg < 4; ++reg) {
            int i = I0 + quad * 4 + reg;      // D row
            int d = dt * 16 + m;              // D col
            float v = acc[dt][reg];
            v = v > 0.f ? v : expm1f(v);      // ELU
            out[((size_t)b * N_ + i) * (H_ * D_) + h * D_ + d] = v;
        }
    }
}

extern "C" void kernel_launch(void* const* d_in, const int* in_sizes, int n_in,
                              void* d_out, int out_size, void* d_ws, size_t ws_size,
                              hipStream_t stream) {
    const float* x   = (const float*)d_in[0];
    const int*   adj = (const int*)d_in[1];
    const float* oh  = (const float*)d_in[2];
    const float* Wq  = (const float*)d_in[3];
    const float* Wk  = (const float*)d_in[4];
    const float* W   = (const float*)d_in[5];
    const float* a   = (const float*)d_in[6];
    float* out = (float*)d_out;
    char* ws = (char*)d_ws;

    float* v1   = (float*)(ws + V1_OFF);
    float* v2   = (float*)(ws + V2_OFF);
    float* e1   = (float*)(ws + E1_OFF);
    float* e2   = (float*)(ws + E2_OFF);
    float* cin  = (float*)(ws + C_OFF);
    float* part = (float*)(ws + PART_OFF);
    unsigned short* WT  = (unsigned short*)(ws + WT_OFF);
    unsigned short* WhT = (unsigned short*)(ws + WHT_OFF);

    k_prep_v<<<9, 256, 0, stream>>>(Wq, Wk, a, v1, v2);
    k_prep_wt<<<256, 256, 0, stream>>>(W, WT);
    k_e12<<<B_ * N_ / 4, 256, 0, stream>>>(x, oh, v1, v2, e1, e2);
    k_wht<<<dim3(128, 4), dim3(64, 4), 0, stream>>>(x, WT, WhT);
    k_colsum<<<dim3(8, 4, 16), 256, 0, stream>>>(adj, e1, e2, part);
    k_recip<<<128, 256, 0, stream>>>(part, cin);
    k_main<<<dim3(128, 4), dim3(64, 4), 0, stream>>>(adj, e1, e2, cin, WhT, out);
}